// Round 1
// baseline (460.967 us; speedup 1.0000x reference)
//
#include <hip/hip_runtime.h>
#include <math.h>

#define BB 16
#define CC 256
#define HH 128
#define WW 128
#define HW (HH*WW)
#define CHW (CC*HW)
#define NQ (BB*CHW)          // 67,108,864 quantized elements
#define NI (BB*HW)           // 262,144 per-pixel elements
#define PIX 64               // pixels per block
#define NTHREADS 512
#define FEPS 1e-6f

__device__ __forceinline__ float quant_one(float x, float fmin, float denom, float lm1) {
    float fn = (x - fmin) / denom;          // IEEE div, matches jax
    float q  = rintf(fn * lm1) / lm1;       // round-half-even like jnp.round
    return q * denom + fmin;
}

__global__ __launch_bounds__(NTHREADS, 4)
void hafis_fused(const float* __restrict__ feat,
                 const float* __restrict__ w1, const float* __restrict__ b1,
                 const float* __restrict__ w2, const float* __restrict__ b2,
                 const float* __restrict__ l1w, const float* __restrict__ l1b,
                 const float* __restrict__ l2w, const float* __restrict__ l2b,
                 const int*   __restrict__ snr_p,
                 float* __restrict__ out)
{
    __shared__ float tile[CC][PIX];       // 64 KB
    __shared__ float pstat[5][8][PIX];    // 10 KB
    __shared__ float4 params[PIX];        // 1 KB

    const int t   = threadIdx.x;
    const int bid = blockIdx.x;           // grid = 16*128*2 = 4096
    const int w0  = (bid & 1) * PIX;
    const int h   = (bid >> 1) & (HH - 1);
    const int b   = bid >> 8;

    const float* base = feat + (size_t)b * CHW + (size_t)h * WW + w0;

    // ---- phase 1: stage (256 x 64) tile into LDS, float4 coalesced ----
    #pragma unroll
    for (int i = 0; i < (CC * PIX / 4) / NTHREADS; ++i) {   // 8 iters
        int idx = i * NTHREADS + t;
        int c = idx >> 4;            // channel
        int v = (idx & 15) * 4;      // float offset within the 64-pixel row
        float4 val = *reinterpret_cast<const float4*>(base + (size_t)c * HW + v);
        *reinterpret_cast<float4*>(&tile[c][v]) = val;
    }
    __syncthreads();

    // ---- phase 2a: partial per-pixel stats (each wave covers 32 channels) ----
    {
        int p   = t & 63;
        int sub = t >> 6;            // 0..7
        float s = 0.f, ss = 0.f, sa = 0.f;
        float mn = INFINITY, mx = -INFINITY;
        #pragma unroll
        for (int k = 0; k < CC / 8; ++k) {
            float x = tile[sub * (CC / 8) + k][p];
            s  += x;
            ss += x * x;
            sa += fabsf(x);
            mn = fminf(mn, x);
            mx = fmaxf(mx, x);
        }
        pstat[0][sub][p] = s;
        pstat[1][sub][p] = ss;
        pstat[2][sub][p] = sa;
        pstat[3][sub][p] = mn;
        pstat[4][sub][p] = mx;
    }
    __syncthreads();

    // ---- phase 2b: combine + per-pixel MLPs (64 active threads) ----
    if (t < PIX) {
        int p = t;
        float s = 0.f, ss = 0.f, sa = 0.f, mn = INFINITY, mx = -INFINITY;
        #pragma unroll
        for (int sub = 0; sub < 8; ++sub) {
            s  += pstat[0][sub][p];
            ss += pstat[1][sub][p];
            sa += pstat[2][sub][p];
            mn = fminf(mn, pstat[3][sub][p]);
            mx = fmaxf(mx, pstat[4][sub][p]);
        }
        float mean_sq  = ss * (1.f / CC);
        float mean_abs = sa * (1.f / CC);
        float mag  = sqrtf(ss) * (1.f / 16.f);              // sqrt(sum)/sqrt(256)
        float var  = (ss - s * s * (1.f / CC)) * (1.f / (CC - 1));  // ddof=1
        float stdv = sqrtf(var);
        float varn = var  / (mean_sq  + FEPS);
        float stdn = stdv / (mean_abs + FEPS);
        mag  = fminf(fmaxf(mag,  0.f), 1.f);
        varn = fminf(fmaxf(varn, 0.f), 1.f);
        stdn = fminf(fmaxf(stdn, 0.f), 1.f);

        // conv fusion 3 -> 16 -> 1 (1x1 convs)
        float acc = b2[0];
        #pragma unroll
        for (int o = 0; o < 16; ++o) {
            float hh2 = w1[o * 3 + 0] * mag + w1[o * 3 + 1] * varn + w1[o * 3 + 2] * stdn + b1[o];
            hh2 = fmaxf(hh2, 0.f);
            acc += w2[o] * hh2;
        }
        float imp = 1.f / (1.f + expf(-acc));

        // bit MLP 3 -> 32 -> 1
        int iv = snr_p[0];
        float snr = (iv > -1000 && iv < 1000) ? (float)iv : __int_as_float(iv);
        float snrn = snr * (1.f / 30.f);
        float acc2 = l2b[0];
        #pragma unroll
        for (int o = 0; o < 32; ++o) {
            float z = l1w[o * 3 + 0] * imp + l1w[o * 3 + 1] * snrn + l1w[o * 3 + 2] * 0.5f + l1b[o];
            z = fmaxf(z, 0.f);
            acc2 += l2w[o] * z;
        }
        float bsig = 1.f / (1.f + expf(-acc2));
        float bits = 4.f + bsig * 8.f;
        float levels = exp2f(bits);
        float lm1 = levels - 1.f;
        float denom = mx - mn + FEPS;

        params[p] = make_float4(mn, denom, lm1, 0.f);

        size_t pix = (size_t)b * HW + (size_t)h * WW + w0 + p;
        out[NQ + pix]      = imp;
        out[NQ + NI + pix] = bits;
    }
    __syncthreads();

    // ---- phase 3: quantize + coalesced float4 stores ----
    {
        int pc   = t & 15;        // 4-pixel chunk
        int crow = t >> 4;        // 0..31
        float4 pr0 = params[4 * pc + 0];
        float4 pr1 = params[4 * pc + 1];
        float4 pr2 = params[4 * pc + 2];
        float4 pr3 = params[4 * pc + 3];
        float* ob = out + (size_t)b * CHW + (size_t)h * WW + w0 + 4 * pc;
        #pragma unroll
        for (int k = 0; k < 8; ++k) {
            int c = crow + 32 * k;
            float4 x = *reinterpret_cast<const float4*>(&tile[c][4 * pc]);
            float4 r;
            r.x = quant_one(x.x, pr0.x, pr0.y, pr0.z);
            r.y = quant_one(x.y, pr1.x, pr1.y, pr1.z);
            r.z = quant_one(x.z, pr2.x, pr2.y, pr2.z);
            r.w = quant_one(x.w, pr3.x, pr3.y, pr3.z);
            *reinterpret_cast<float4*>(ob + (size_t)c * HW) = r;
        }
    }
}

extern "C" void kernel_launch(void* const* d_in, const int* in_sizes, int n_in,
                              void* d_out, int out_size, void* d_ws, size_t ws_size,
                              hipStream_t stream) {
    const float* feat = (const float*)d_in[0];
    const float* w1   = (const float*)d_in[1];
    const float* b1   = (const float*)d_in[2];
    const float* w2   = (const float*)d_in[3];
    const float* b2   = (const float*)d_in[4];
    const float* l1w  = (const float*)d_in[5];
    const float* l1b  = (const float*)d_in[6];
    const float* l2w  = (const float*)d_in[7];
    const float* l2b  = (const float*)d_in[8];
    const int*   snr  = (const int*)d_in[9];
    float* out = (float*)d_out;

    dim3 grid(BB * HH * (WW / PIX));   // 4096
    dim3 block(NTHREADS);
    hipLaunchKernelGGL(hafis_fused, grid, block, 0, stream,
                       feat, w1, b1, w2, b2, l1w, l1b, l2w, l2b, snr, out);
}